// Round 11
// baseline (835.651 us; speedup 1.0000x reference)
//
#include <hip/hip_runtime.h>

typedef __attribute__((ext_vector_type(8))) _Float16 f16x8;
typedef __attribute__((ext_vector_type(16))) float f32x16;

#define B_    8
#define LSEQ  2048
#define DIM   1024
#define QBLK  64
#define KBLK  128
#define NKB   (LSEQ / KBLK)   // 16
#define NBAND 8

// K/V image geometry: 32KB tiles (128x128 fp16, 4-bit row-XOR swizzle baked in)
#define TILE_US   16384        // ushorts per tile
#define KIMG_US   ((size_t)2 * 8 * 16 * 8 * TILE_US)   // 64 MB
#define WS_NEED   ((size_t)2 * KIMG_US * 2)            // 128 MB

static __device__ __forceinline__ unsigned pk2(float a, float b) {
    return __builtin_bit_cast(unsigned, __builtin_amdgcn_cvt_pkrtz(a, b));
}

#define VMCNT(n) asm volatile("s_waitcnt vmcnt(" #n ")" ::: "memory")
#define LGKM0()  asm volatile("s_waitcnt lgkmcnt(0)" ::: "memory")
#define BAR()    do { asm volatile("" ::: "memory"); __builtin_amdgcn_s_barrier(); \
                      asm volatile("" ::: "memory"); } while (0)

static __device__ __forceinline__ int s3(int x) { return x >= 3 ? x - 3 : x; }

static __device__ __forceinline__ void gll16(const void* g, void* l) {
    __builtin_amdgcn_global_load_lds(
        (const __attribute__((address_space(1))) void*)g,
        (__attribute__((address_space(3))) void*)l, 16, 0, 0);
}

// 32KB tile: 8 waves x 4 ops x 1KB ; 16KB tile: 8 waves x 2 ops x 1KB
// (per-wave op counts: KQ item = 4+2 = 6, V item = 4 — the VMCNT constants)
static __device__ __forceinline__ void issue32(const unsigned short* gt, unsigned short* lb, int w, int lane) {
    #pragma unroll
    for (int j = 0; j < 4; ++j) {
        const int off = (w * 4 + j) * 1024;
        gll16((const char*)gt + off + lane * 16, (char*)lb + off);
    }
}
static __device__ __forceinline__ void issue16(const unsigned short* gt, unsigned short* lb, int w, int lane) {
    #pragma unroll
    for (int j = 0; j < 2; ++j) {
        const int off = (w * 2 + j) * 1024;
        gll16((const char*)gt + off + lane * 16, (char*)lb + off);
    }
}

// ============ prepass: fp32 -> fp16 swizzled LDS-image tiles (4-bit row XOR) ============
__global__ __launch_bounds__(256)
void prepass(const float* __restrict__ Sp, const float* __restrict__ Dp,
             unsigned short* __restrict__ Kimg, unsigned short* __restrict__ Vimg)
{
    const int blk = blockIdx.x;            // 2*8*16*8 = 2048
    const int dc = blk & 7;
    const int kb = (blk >> 3) & 15;
    const int b  = (blk >> 7) & 7;
    const int m  = blk >> 10;
    const float* src = (m ? Dp : Sp) + ((size_t)b * LSEQ + kb * 128) * DIM + dc * 128;
    unsigned short* kt = Kimg + (size_t)((((m * 8 + b) * 16 + kb) * 8) + dc) * TILE_US;
    unsigned short* vt = Vimg + (size_t)((((m * 8 + b) * 8 + dc) * 16) + kb) * TILE_US;

    __shared__ unsigned short tile[128 * 132];
    const int t = threadIdx.x;

    #pragma unroll
    for (int i = 0; i < 16; ++i) {
        const int idx = t + i * 256;
        const int r = idx >> 5;
        const int c4 = (idx & 31) << 2;
        const float4 v = *(const float4*)(src + (size_t)r * DIM + c4);
        const unsigned lo = pk2(v.x, v.y), hi2 = pk2(v.z, v.w);
        *(uint2*)(kt + r * 128 + (c4 ^ ((r & 15) << 3))) = make_uint2(lo, hi2);
        *(uint2*)(&tile[r * 132 + c4]) = make_uint2(lo, hi2);
    }
    __syncthreads();
    #pragma unroll
    for (int i = 0; i < 32; ++i) {
        const int widx = t + i * 256;
        const int dcl = widx >> 6;
        const int wk  = widx & 63;
        const unsigned a  = tile[(wk * 2) * 132 + dcl];
        const unsigned bb = tile[(wk * 2 + 1) * 132 + dcl];
        ((unsigned*)vt)[dcl * 64 + (wk ^ ((dcl & 15) << 2))] = a | (bb << 16);
    }
}

// ============ main: continuous ring across kb (R4 in-phase order preserved) ============
// phase: BAR [publish item p (waited last phase); close readers of issue slot];
//        issue item p+2; VMCNT(N) [drain item p+1, issued 1 phase ago];
//        MFMA item p.
__global__ __launch_bounds__(512, 2)
void coattn_main(const float* __restrict__ Sp, const float* __restrict__ Dp,
                 float* __restrict__ outp,
                 const unsigned short* __restrict__ Kimg,
                 const unsigned short* __restrict__ Vimg)
{
    const int s   = blockIdx.x;
    const int g   = (s & 7) | ((s >> 8) << 3);
    const int qb  = (s >> 3) & 31;
    const int dir = g >> 3;
    const int b   = g & 7;
    const int mat_k = dir;
    const int mat_q = 1 - dir;

    const float* Qg = (dir ? Sp : Dp) + (size_t)b * LSEQ * DIM;
    float* Og = outp + (size_t)dir * ((size_t)B_ * LSEQ * DIM) + (size_t)b * LSEQ * DIM;
    const int q0 = qb * QBLK;

    const unsigned short* kbase = Kimg + (size_t)(mat_k * 8 + b) * 16 * 8 * TILE_US;
    const unsigned short* qbase = Kimg + (size_t)(mat_q * 8 + b) * 16 * 8 * TILE_US
                                + (size_t)(qb >> 1) * 8 * TILE_US + (size_t)(qb & 1) * 8192;
    const unsigned short* vbase = Vimg + (size_t)(mat_k * 8 + b) * 8 * 16 * TILE_US;

    __shared__ unsigned short Rr[3][16384];   // 96 KB: K-chunks / V-bands ring
    __shared__ unsigned short QR_[3][8192];   // 48 KB: Q-chunks ring (rotating P alias)
    __shared__ float redmax[2][4][32];
    __shared__ float redsum[2][4][32];
    __shared__ float alf[QBLK];

    const int t    = threadIdx.x;
    const int lane = t & 63;
    const int w    = t >> 6;
    const int l31  = lane & 31;
    const int hi   = lane >> 5;
    const int ksub = w & 3;
    const int qh   = w >> 2;

    const int krow = ksub * 32 + l31;
    const int qrow = qh * 32 + l31;
    const int kswz = (krow & 15) << 3;
    const int qswz = (qrow & 15) << 3;
    const int dcl  = ksub * 32 + l31;
    const int vswz = (dcl & 15) << 3;

    f32x16 O[NBAND];
    #pragma unroll
    for (int i = 0; i < NBAND; ++i)
        #pragma unroll
        for (int r = 0; r < 16; ++r) O[i][r] = 0.0f;

    float m_run = -INFINITY, l_run = 0.0f;

    #define QK_MMA(RS, QS)                                                        \
    do {                                                                          \
        const unsigned short* Kb = Rr[RS];                                        \
        const unsigned short* Qb = QR_[QS];                                       \
        __builtin_amdgcn_s_setprio(1);                                            \
        _Pragma("unroll")                                                         \
        for (int kc = 0; kc < 8; ++kc) {                                          \
            const int d0 = kc * 16 + hi * 8;                                      \
            f16x8 a  = *(const f16x8*)&Kb[krow * 128 + (d0 ^ kswz)];              \
            f16x8 bq = *(const f16x8*)&Qb[qrow * 128 + (d0 ^ qswz)];              \
            C = __builtin_amdgcn_mfma_f32_32x32x16_f16(a, bq, C, 0, 0, 0);        \
        }                                                                         \
        __builtin_amdgcn_s_setprio(0);                                            \
    } while (0)

    #define PV_MMA(BAND, RS)                                                      \
    do {                                                                          \
        const unsigned short* Vb = Rr[RS];                                        \
        __builtin_amdgcn_s_setprio(1);                                            \
        _Pragma("unroll")                                                         \
        for (int kc = 0; kc < 8; ++kc) {                                          \
            const int kk0 = kc * 16 + hi * 8;                                     \
            f16x8 vb = *(const f16x8*)&Vb[dcl * 128 + (kk0 ^ vswz)];              \
            O[BAND] = __builtin_amdgcn_mfma_f32_32x32x16_f16(pa[kc], vb, O[BAND], 0, 0, 0); \
        }                                                                         \
        __builtin_amdgcn_s_setprio(0);                                            \
    } while (0)

    // QK phase P (0..5): Rr item P -> slot s3(sb+P%3), QR item P -> s3(qsb+P%3)
    #define QK_PHASE(P)                                                           \
    do {                                                                          \
        BAR();                                                                    \
        issue32(kt + (P + 2) * TILE_US, Rr[s3(sb + ((P + 2) % 3))], w, lane);     \
        issue16(qbase + (P + 2) * TILE_US, QR_[s3(qsb + ((P + 2) % 3))], w, lane);\
        VMCNT(6);                                                                 \
        QK_MMA(s3(sb + (P % 3)), s3(qsb + (P % 3)));                              \
    } while (0)

    // PV phase, band V (1..5): V item 8+V -> slot s3(sb+(8+V)%3); issue item 10+V
    #define PV_PHASE(V)                                                           \
    do {                                                                          \
        BAR();                                                                    \
        issue32(vbase + (size_t)((V + 2) * 16 + kb) * TILE_US,                    \
                Rr[s3(sb + ((V + 10) % 3))], w, lane);                            \
        VMCNT(4);                                                                 \
        PV_MMA(V, s3(sb + ((V + 8) % 3)));                                        \
    } while (0)

    // one-time prologue: KQ0 -> slots (0,0); KQ1 -> (1,1); drain own KQ0
    issue32(kbase + 0 * TILE_US, Rr[0], w, lane);
    issue16(qbase + 0 * TILE_US, QR_[0], w, lane);
    issue32(kbase + 1 * TILE_US, Rr[1], w, lane);
    issue16(qbase + 1 * TILE_US, QR_[1], w, lane);
    VMCNT(6);
    BAR();

    int sb = 0, qsb = 0;   // ring bases; advance 1 / 2 per kb (16%3, 8%3)

    #pragma unroll 1
    for (int kb = 0; kb < NKB; ++kb) {
        const unsigned short* kt = kbase + (size_t)kb * 8 * TILE_US;

        f32x16 C;
        #pragma unroll
        for (int r = 0; r < 16; ++r) C[r] = 0.0f;

        // ---- QK phases 0..7 ----
        QK_PHASE(0); QK_PHASE(1); QK_PHASE(2);
        QK_PHASE(3); QK_PHASE(4); QK_PHASE(5);
        // phase 6: issue V0 (Rr item 8 -> s3(sb+2)); drain KQ7
        BAR();
        issue32(vbase + (size_t)(0 * 16 + kb) * TILE_US, Rr[s3(sb + 2)], w, lane);
        VMCNT(4);
        QK_MMA(s3(sb + 0), s3(qsb + 0));
        // phase 7: issue V1 (item 9 -> s3(sb+0)); drain V0
        BAR();
        issue32(vbase + (size_t)(1 * 16 + kb) * TILE_US, Rr[s3(sb + 0)], w, lane);
        VMCNT(4);
        QK_MMA(s3(sb + 1), s3(qsb + 1));

        // ---- online softmax (lgkm-only barriers: V1 DMA stays in flight) ----
        unsigned short* Plds = QR_[s3(qsb + 1)];   // Q7's slot; free after phase 7,
                                                   // untouched by phases 14/15 issues
        float rm = -INFINITY;
        #pragma unroll
        for (int r = 0; r < 16; ++r) rm = fmaxf(rm, C[r]);
        rm = fmaxf(rm, __shfl_xor(rm, 32));
        if (lane < 32) redmax[qh][ksub][l31] = rm;
        LGKM0(); BAR();

        const float bm = fmaxf(fmaxf(redmax[qh][0][l31], redmax[qh][1][l31]),
                               fmaxf(redmax[qh][2][l31], redmax[qh][3][l31]));
        const float mn = fmaxf(m_run, bm);
        const float al = __expf(m_run - mn);
        float p[16];
        float ps = 0.0f;
        #pragma unroll
        for (int r = 0; r < 16; ++r) { p[r] = __expf(C[r] - mn); ps += p[r]; }
        ps += __shfl_xor(ps, 32);
        if (lane < 32) {
            redsum[qh][ksub][l31] = ps;
            if (ksub == 0) alf[qh * 32 + l31] = al;
        }
        {   // P (fp16) -> LDS [q][k]
            #pragma unroll
            for (int rp = 0; rp < 8; ++rp) {
                const int r  = rp * 2;
                const int kk = ksub * 32 + (r & 3) + 8 * (r >> 2) + 4 * hi;
                *(unsigned*)&Plds[qrow * KBLK + (kk ^ qswz)] = pk2(p[r], p[r + 1]);
            }
        }
        LGKM0(); BAR();

        const float bs = redsum[qh][0][l31] + redsum[qh][1][l31] +
                         redsum[qh][2][l31] + redsum[qh][3][l31];
        l_run = l_run * al + bs;
        m_run = mn;

        float alr[16];
        #pragma unroll
        for (int r = 0; r < 16; ++r)
            alr[r] = alf[qh * 32 + (r & 3) + 8 * (r >> 2) + 4 * hi];
        #pragma unroll
        for (int i = 0; i < NBAND; ++i)
            #pragma unroll
            for (int r = 0; r < 16; ++r) O[i][r] *= alr[r];

        f16x8 pa[8];
        #pragma unroll
        for (int kc = 0; kc < 8; ++kc) {
            const int kk0 = kc * 16 + hi * 8;
            pa[kc] = *(const f16x8*)&Plds[qrow * KBLK + (kk0 ^ qswz)];
        }

        // ---- PV bands 0..7 ----
        // band 0 (softmax bar2 serves as its barrier): issue V2 (item 10 -> s3(sb+1));
        // VMCNT(4) drains V0,V1 (issued >=2 phases + softmax ago)
        issue32(vbase + (size_t)(2 * 16 + kb) * TILE_US, Rr[s3(sb + 1)], w, lane);
        VMCNT(4);
        PV_MMA(0, s3(sb + 2));
        PV_PHASE(1); PV_PHASE(2); PV_PHASE(3); PV_PHASE(4); PV_PHASE(5);
        // band 6 (phase 14): issue next-kb KQ0 (Rr item 16 -> s3(sb+1); Q -> s3(qsb+2))
        BAR();
        if (kb + 1 < NKB) {
            const unsigned short* ktn = kbase + (size_t)(kb + 1) * 8 * TILE_US;
            issue32(ktn + 0 * TILE_US, Rr[s3(sb + 1)], w, lane);
            issue16(qbase + 0 * TILE_US, QR_[s3(qsb + 2)], w, lane);
            VMCNT(6);                              // drain V7
        } else {
            VMCNT(0);                              // drain V7 (nothing else in flight)
        }
        PV_MMA(6, s3(sb + 2));
        // band 7 (phase 15): issue next-kb KQ1 (item 17 -> s3(sb+2); Q -> qsb)
        BAR();
        if (kb + 1 < NKB) {
            const unsigned short* ktn = kbase + (size_t)(kb + 1) * 8 * TILE_US;
            issue32(ktn + 1 * TILE_US, Rr[s3(sb + 2)], w, lane);
            issue16(qbase + 1 * TILE_US, QR_[qsb], w, lane);
            VMCNT(6);                              // drain next-kb KQ0
        } else {
            VMCNT(0);
        }
        PV_MMA(7, sb);

        sb = s3(sb + 1);     // (kb+1)*16 % 3
        qsb = s3(qsb + 2);   // (kb+1)*8 % 3
    }

    // ---- epilogue: out = residual(Q) + O / l ----
    __syncthreads();
    if (lane < 32 && ksub == 0) alf[qh * 32 + l31] = 1.0f / l_run;
    __syncthreads();
    #pragma unroll
    for (int r = 0; r < 16; ++r) {
        const int qr = qh * 32 + (r & 3) + 8 * (r >> 2) + 4 * hi;
        const float il = alf[qr];
        const size_t rowoff = (size_t)(q0 + qr) * DIM;
        #pragma unroll
        for (int band = 0; band < NBAND; ++band) {
            const int dcol = band * 128 + ksub * 32 + l31;
            Og[rowoff + dcol] = Qg[rowoff + dcol] + O[band][r] * il;
        }
    }
    #undef QK_MMA
    #undef PV_MMA
    #undef QK_PHASE
    #undef PV_PHASE
}

// ============ fallback (round-2 kernel, verbatim — used if ws too small) ============
#define NDC   8

__global__ __launch_bounds__(512, 2)
void coattn_fb(const float* __restrict__ Sp, const float* __restrict__ Dp,
               float* __restrict__ outp)
{
    const int s   = blockIdx.x;
    const int g   = (s & 7) | ((s >> 8) << 3);
    const int qb  = (s >> 3) & 31;
    const int dir = g >> 3;
    const int b   = g & 7;

    const float* Qg = (dir ? Sp : Dp) + (size_t)b * LSEQ * DIM;
    const float* Kg = (dir ? Dp : Sp) + (size_t)b * LSEQ * DIM;
    float* Og = outp + (size_t)dir * ((size_t)B_ * LSEQ * DIM) + (size_t)b * LSEQ * DIM;
    const int q0 = qb * QBLK;

    __shared__ unsigned short Klds[KBLK * 128];
    __shared__ unsigned short Qlds[QBLK * 128];
    __shared__ unsigned short Plds[QBLK * KBLK];
    __shared__ unsigned short Vlds[128 * KBLK];
    __shared__ float redmax[2][4][32];
    __shared__ float redsum[2][4][32];
    __shared__ float alf[QBLK];

    const int t    = threadIdx.x;
    const int lane = t & 63;
    const int w    = t >> 6;
    const int l31  = lane & 31;
    const int hi   = lane >> 5;
    const int ksub = w & 3;
    const int qh   = w >> 2;

    f32x16 O[NBAND];
    #pragma unroll
    for (int i = 0; i < NBAND; ++i)
        #pragma unroll
        for (int r = 0; r < 16; ++r) O[i][r] = 0.0f;

    float m_run = -INFINITY, l_run = 0.0f;

    const int srow = t >> 4;
    const int fcol = (t & 15) << 2;
    const int vmm  = t & 31;
    const int vkp0 = t >> 5;

    const int krow = ksub * 32 + l31;
    const int qrow = qh * 32 + l31;

    for (int kb = 0; kb < NKB; ++kb) {
        const int k0g = kb * KBLK;
        f32x16 C;
        #pragma unroll
        for (int r = 0; r < 16; ++r) C[r] = 0.0f;

        float4 kreg[8], qreg[4];
        #pragma unroll
        for (int pass = 0; pass < 4; ++pass)
            #pragma unroll
            for (int h = 0; h < 2; ++h)
                kreg[pass * 2 + h] = *(const float4*)(Kg + (size_t)(k0g + pass * 32 + srow) * DIM + fcol + h * 64);
        #pragma unroll
        for (int pass = 0; pass < 2; ++pass)
            #pragma unroll
            for (int h = 0; h < 2; ++h)
                qreg[pass * 2 + h] = *(const float4*)(Qg + (size_t)(q0 + pass * 32 + srow) * DIM + fcol + h * 64);

        #pragma unroll 1
        for (int dc = 0; dc < NDC; ++dc) {
            __syncthreads();
            #pragma unroll
            for (int pass = 0; pass < 4; ++pass)
                #pragma unroll
                for (int h = 0; h < 2; ++h) {
                    const int row = pass * 32 + srow;
                    const int d   = fcol + h * 64;
                    const float4 v = kreg[pass * 2 + h];
                    *(uint2*)&Klds[row * 128 + (d ^ ((row & 7) << 3))] =
                        make_uint2(pk2(v.x, v.y), pk2(v.z, v.w));
                }
            #pragma unroll
            for (int pass = 0; pass < 2; ++pass)
                #pragma unroll
                for (int h = 0; h < 2; ++h) {
                    const int row = pass * 32 + srow;
                    const int d   = fcol + h * 64;
                    const float4 v = qreg[pass * 2 + h];
                    *(uint2*)&Qlds[row * 128 + (d ^ ((row & 7) << 3))] =
                        make_uint2(pk2(v.x, v.y), pk2(v.z, v.w));
                }
            __syncthreads();
            if (dc + 1 < NDC) {
                const int dbase = (dc + 1) * 128;
                #pragma unroll
                for (int pass = 0; pass < 4; ++pass)
                    #pragma unroll
                    for (int h = 0; h < 2; ++h)
                        kreg[pass * 2 + h] = *(const float4*)(Kg + (size_t)(k0g + pass * 32 + srow) * DIM + dbase + fcol + h * 64);
                #pragma unroll
                for (int pass = 0; pass < 2; ++pass)
                    #pragma unroll
                    for (int h = 0; h < 2; ++h)
                        qreg[pass * 2 + h] = *(const float4*)(Qg + (size_t)(q0 + pass * 32 + srow) * DIM + dbase + fcol + h * 64);
            }
            #pragma unroll
            for (int kc = 0; kc < 8; ++kc) {
                const int d0 = kc * 16 + hi * 8;
                f16x8 a  = *(const f16x8*)&Klds[krow * 128 + (d0 ^ ((krow & 7) << 3))];
                f16x8 bq = *(const f16x8*)&Qlds[qrow * 128 + (d0 ^ ((qrow & 7) << 3))];
                C = __builtin_amdgcn_mfma_f32_32x32x16_f16(a, bq, C, 0, 0, 0);
            }
        }

        float rm = -INFINITY;
        #pragma unroll
        for (int r = 0; r < 16; ++r) rm = fmaxf(rm, C[r]);
        rm = fmaxf(rm, __shfl_xor(rm, 32));
        if (lane < 32) redmax[qh][ksub][l31] = rm;
        __syncthreads();

        const float bm = fmaxf(fmaxf(redmax[qh][0][l31], redmax[qh][1][l31]),
                               fmaxf(redmax[qh][2][l31], redmax[qh][3][l31]));
        const float mn = fmaxf(m_run, bm);
        const float al = __expf(m_run - mn);
        float p[16];
        float ps = 0.0f;
        #pragma unroll
        for (int r = 0; r < 16; ++r) { p[r] = __expf(C[r] - mn); ps += p[r]; }
        ps += __shfl_xor(ps, 32);
        if (lane < 32) {
            redsum[qh][ksub][l31] = ps;
            if (ksub == 0) alf[qh * 32 + l31] = al;
        }
        {
            #pragma unroll
            for (int rp = 0; rp < 8; ++rp) {
                const int r  = rp * 2;
                const int kk = ksub * 32 + (r & 3) + 8 * (r >> 2) + 4 * hi;
                *(unsigned*)&Plds[qrow * KBLK + (kk ^ ((qrow & 7) << 3))] = pk2(p[r], p[r + 1]);
            }
        }
        __syncthreads();

        const float bs = redsum[qh][0][l31] + redsum[qh][1][l31] +
                         redsum[qh][2][l31] + redsum[qh][3][l31];
        l_run = l_run * al + bs;
        m_run = mn;

        float alr[16];
        #pragma unroll
        for (int r = 0; r < 16; ++r)
            alr[r] = alf[qh * 32 + (r & 3) + 8 * (r >> 2) + 4 * hi];
        #pragma unroll
        for (int i = 0; i < NBAND; ++i)
            #pragma unroll
            for (int r = 0; r < 16; ++r) O[i][r] *= alr[r];

        f16x8 pa[8];
        #pragma unroll
        for (int kc = 0; kc < 8; ++kc) {
            const int kk0 = kc * 16 + hi * 8;
            pa[kc] = *(const f16x8*)&Plds[qrow * KBLK + (kk0 ^ ((qrow & 7) << 3))];
        }

        float4 v0s[4], v1s[4];
        #pragma unroll
        for (int pass = 0; pass < 4; ++pass) {
            const int kp = pass * 16 + vkp0;
            v0s[pass] = *(const float4*)(Kg + (size_t)(k0g + 2 * kp) * DIM + vmm * 4);
            v1s[pass] = *(const float4*)(Kg + (size_t)(k0g + 2 * kp + 1) * DIM + vmm * 4);
        }

        #pragma unroll
        for (int band = 0; band < NBAND; ++band) {
            __syncthreads();
            #pragma unroll
            for (int pass = 0; pass < 4; ++pass) {
                const int kp = pass * 16 + vkp0;
                const float* a0 = (const float*)&v0s[pass];
                const float* a1 = (const float*)&v1s[pass];
                #pragma unroll
                for (int j = 0; j < 4; ++j) {
                    const int dclw = vmm * 4 + j;
                    *(unsigned*)&Vlds[dclw * KBLK + ((2 * kp) ^ ((dclw & 7) << 3))] = pk2(a0[j], a1[j]);
                }
            }
            __syncthreads();
            if (band + 1 < NBAND) {
                const int cb = (band + 1) * 128;
                #pragma unroll
                for (int pass = 0; pass < 4; ++pass) {
                    const int kp = pass * 16 + vkp0;
                    v0s[pass] = *(const float4*)(Kg + (size_t)(k0g + 2 * kp) * DIM + cb + vmm * 4);
                    v1s[pass] = *(const float4*)(Kg + (size_t)(k0g + 2 * kp + 1) * DIM + cb + vmm * 4);
                }
            }
            const int dclr = ksub * 32 + l31;
            const int sw  = (dclr & 7) << 3;
            #pragma unroll
            for (int kc = 0; kc < 8; ++kc) {
                const int kk0 = kc * 16 + hi * 8;
                f16x8 vb = *(const f16x8*)&Vlds[dclr * KBLK + (kk0 ^ sw)];
                O[band] = __builtin_amdgcn_mfma_f32_32x32x16_f16(pa[kc], vb, O[band], 0, 0, 0);
            }
        }
    }

    if (lane < 32 && ksub == 0) alf[qh * 32 + l31] = 1.0f / l_run;
    __syncthreads();
    #pragma unroll
    for (int r = 0; r < 16; ++r) {
        const int qr = qh * 32 + (r & 3) + 8 * (r >> 2) + 4 * hi;
        const float il = alf[qr];
        const size_t rowoff = (size_t)(q0 + qr) * DIM;
        #pragma unroll
        for (int band = 0; band < NBAND; ++band) {
            const int dcol = band * 128 + ksub * 32 + l31;
            Og[rowoff + dcol] = Qg[rowoff + dcol] + O[band][r] * il;
        }
    }
}

extern "C" void kernel_launch(void* const* d_in, const int* in_sizes, int n_in,
                              void* d_out, int out_size, void* d_ws, size_t ws_size,
                              hipStream_t stream) {
    const float* S = (const float*)d_in[0];
    const float* D = (const float*)d_in[1];
    float* out = (float*)d_out;
    if (ws_size >= WS_NEED) {
        unsigned short* Kimg = (unsigned short*)d_ws;
        unsigned short* Vimg = Kimg + KIMG_US;
        prepass<<<dim3(2048, 1, 1), dim3(256, 1, 1), 0, stream>>>(S, D, Kimg, Vimg);
        coattn_main<<<dim3(512, 1, 1), dim3(512, 1, 1), 0, stream>>>(S, D, out, Kimg, Vimg);
    } else {
        coattn_fb<<<dim3(512, 1, 1), dim3(512, 1, 1), 0, stream>>>(S, D, out);
    }
}

// Round 12
// 566.259 us; speedup vs baseline: 1.4757x; 1.4757x over previous
//
#include <hip/hip_runtime.h>

typedef __attribute__((ext_vector_type(8))) _Float16 f16x8;
typedef __attribute__((ext_vector_type(16))) float f32x16;

#define B_    8
#define LSEQ  2048
#define DIM   1024
#define QBLK  64
#define KBLK  128
#define NKB   (LSEQ / KBLK)   // 16
#define NBAND 8
#define SHIFT 104.0f

// K/V image geometry: 32KB tiles (128x128 fp16, 4-bit row-XOR swizzle baked in)
#define TILE_US   16384        // ushorts per tile
#define KIMG_US   ((size_t)2 * 8 * 16 * 8 * TILE_US)   // 64 MB
#define WS_NEED   ((size_t)2 * KIMG_US * 2)            // 128 MB (old path)
#define WS_NEW    ((size_t)3 * KIMG_US * 2)            // 192 MB (new path: + scores)

static __device__ __forceinline__ unsigned pk2(float a, float b) {
    return __builtin_bit_cast(unsigned, __builtin_amdgcn_cvt_pkrtz(a, b));
}

#define VMCNT(n) asm volatile("s_waitcnt vmcnt(" #n ")" ::: "memory")
#define LGKM0()  asm volatile("s_waitcnt lgkmcnt(0)" ::: "memory")
#define BAR()    do { asm volatile("" ::: "memory"); __builtin_amdgcn_s_barrier(); \
                      asm volatile("" ::: "memory"); } while (0)

static __device__ __forceinline__ void gll16(const void* g, void* l) {
    __builtin_amdgcn_global_load_lds(
        (const __attribute__((address_space(1))) void*)g,
        (__attribute__((address_space(3))) void*)l, 16, 0, 0);
}

static __device__ __forceinline__ void issue32(const unsigned short* gt, unsigned short* lb, int w, int lane) {
    #pragma unroll
    for (int j = 0; j < 4; ++j) {
        const int off = (w * 4 + j) * 1024;
        gll16((const char*)gt + off + lane * 16, (char*)lb + off);
    }
}
static __device__ __forceinline__ void issue16(const unsigned short* gt, unsigned short* lb, int w, int lane) {
    #pragma unroll
    for (int j = 0; j < 2; ++j) {
        const int off = (w * 2 + j) * 1024;
        gll16((const char*)gt + off + lane * 16, (char*)lb + off);
    }
}

// ============ prepass: fp32 -> fp16 swizzled images (verbatim R10) ============
__global__ __launch_bounds__(256)
void prepass(const float* __restrict__ Sp, const float* __restrict__ Dp,
             unsigned short* __restrict__ Kimg, unsigned short* __restrict__ Vimg)
{
    const int blk = blockIdx.x;            // 2*8*16*8 = 2048
    const int dc = blk & 7;
    const int kb = (blk >> 3) & 15;
    const int b  = (blk >> 7) & 7;
    const int m  = blk >> 10;
    const float* src = (m ? Dp : Sp) + ((size_t)b * LSEQ + kb * 128) * DIM + dc * 128;
    unsigned short* kt = Kimg + (size_t)((((m * 8 + b) * 16 + kb) * 8) + dc) * TILE_US;
    unsigned short* vt = Vimg + (size_t)((((m * 8 + b) * 8 + dc) * 16) + kb) * TILE_US;

    __shared__ unsigned short tile[128 * 132];
    const int t = threadIdx.x;

    #pragma unroll
    for (int i = 0; i < 16; ++i) {
        const int idx = t + i * 256;
        const int r = idx >> 5;
        const int c4 = (idx & 31) << 2;
        const float4 v = *(const float4*)(src + (size_t)r * DIM + c4);
        const unsigned lo = pk2(v.x, v.y), hi2 = pk2(v.z, v.w);
        *(uint2*)(kt + r * 128 + (c4 ^ ((r & 15) << 3))) = make_uint2(lo, hi2);
        *(uint2*)(&tile[r * 132 + c4]) = make_uint2(lo, hi2);
    }
    __syncthreads();
    #pragma unroll
    for (int i = 0; i < 32; ++i) {
        const int widx = t + i * 256;
        const int dcl = widx >> 6;
        const int wk  = widx & 63;
        const unsigned a  = tile[(wk * 2) * 132 + dcl];
        const unsigned bb = tile[(wk * 2 + 1) * 132 + dcl];
        ((unsigned*)vt)[dcl * 64 + (wk ^ ((dcl & 15) << 2))] = a | (bb << 16);
    }
}

// ============ P1: scores = D·S^T once, shifted fp16 to ws (QK core = R10) ============
__global__ __launch_bounds__(512, 2)
void coattn_qk(const unsigned short* __restrict__ Kimg,
               unsigned short* __restrict__ scores)
{
    const int s  = blockIdx.x;     // 256 = qb32 x b8
    const int b  = s & 7;
    const int qb = s >> 3;
    const int q0 = qb * QBLK;

    const unsigned short* kbase = Kimg + (size_t)(0 * 8 + b) * 16 * 8 * TILE_US;   // K = S
    const unsigned short* qbase = Kimg + (size_t)(1 * 8 + b) * 16 * 8 * TILE_US    // Q = D
                                + (size_t)(qb >> 1) * 8 * TILE_US + (size_t)(qb & 1) * 8192;
    unsigned short* scb = scores + (size_t)b * LSEQ * LSEQ;

    __shared__ unsigned short Rr[3][16384];
    __shared__ unsigned short QR_[3][8192];

    const int t    = threadIdx.x;
    const int lane = t & 63;
    const int w    = t >> 6;
    const int l31  = lane & 31;
    const int hi   = lane >> 5;
    const int ksub = w & 3;
    const int qh   = w >> 2;

    const int krow = ksub * 32 + l31;
    const int qrow = qh * 32 + l31;
    const int kswz = (krow & 15) << 3;
    const int qswz = (qrow & 15) << 3;

    #define QK_MMA(SLOT)                                                          \
    do {                                                                          \
        const unsigned short* Kb = Rr[SLOT];                                      \
        const unsigned short* Qb = QR_[SLOT];                                     \
        __builtin_amdgcn_s_setprio(1);                                            \
        _Pragma("unroll")                                                         \
        for (int kc = 0; kc < 8; ++kc) {                                          \
            const int d0 = kc * 16 + hi * 8;                                      \
            f16x8 a  = *(const f16x8*)&Kb[krow * 128 + (d0 ^ kswz)];              \
            f16x8 bq = *(const f16x8*)&Qb[qrow * 128 + (d0 ^ qswz)];              \
            C = __builtin_amdgcn_mfma_f32_32x32x16_f16(a, bq, C, 0, 0, 0);        \
        }                                                                         \
        __builtin_amdgcn_s_setprio(0);                                            \
    } while (0)

    #pragma unroll 1
    for (int kb = 0; kb < NKB; ++kb) {
        const unsigned short* kt = kbase + (size_t)kb * 8 * TILE_US;

        f32x16 C;
        #pragma unroll
        for (int r = 0; r < 16; ++r) C[r] = 0.0f;

        BAR();
        issue32(kt + 0 * TILE_US, Rr[0], w, lane);
        issue16(qbase + 0 * TILE_US, QR_[0], w, lane);
        issue32(kt + 1 * TILE_US, Rr[1], w, lane);
        issue16(qbase + 1 * TILE_US, QR_[1], w, lane);
        VMCNT(6);
        BAR();

        issue32(kt + 2 * TILE_US, Rr[2], w, lane);   // phase 0
        issue16(qbase + 2 * TILE_US, QR_[2], w, lane);
        VMCNT(6);
        QK_MMA(0);

        BAR();                                       // phase 1
        issue32(kt + 3 * TILE_US, Rr[0], w, lane);
        issue16(qbase + 3 * TILE_US, QR_[0], w, lane);
        VMCNT(6);
        QK_MMA(1);

        BAR();                                       // phase 2
        issue32(kt + 4 * TILE_US, Rr[1], w, lane);
        issue16(qbase + 4 * TILE_US, QR_[1], w, lane);
        VMCNT(6);
        QK_MMA(2);

        BAR();                                       // phase 3
        issue32(kt + 5 * TILE_US, Rr[2], w, lane);
        issue16(qbase + 5 * TILE_US, QR_[2], w, lane);
        VMCNT(6);
        QK_MMA(0);

        BAR();                                       // phase 4
        issue32(kt + 6 * TILE_US, Rr[0], w, lane);
        issue16(qbase + 6 * TILE_US, QR_[0], w, lane);
        VMCNT(6);
        QK_MMA(1);

        BAR();                                       // phase 5
        issue32(kt + 7 * TILE_US, Rr[1], w, lane);
        issue16(qbase + 7 * TILE_US, QR_[1], w, lane);
        VMCNT(6);
        QK_MMA(2);

        BAR();                                       // phase 6 (no issue)
        VMCNT(0);
        QK_MMA(0);

        BAR();                                       // phase 7
        QK_MMA(1);

        // write shifted fp16 scores, plain row-major [D-row][S-col]
        {
            const size_t rowoff = (size_t)(q0 + 32 * qh + l31) * LSEQ + kb * 128 + 32 * ksub;
            #pragma unroll
            for (int rp = 0; rp < 8; ++rp) {
                const int r  = rp * 2;
                const int kk = (r & 3) + 8 * (r >> 2) + 4 * hi;
                *(unsigned*)(scb + rowoff + kk) = pk2(C[r] - SHIFT, C[r + 1] - SHIFT);
            }
        }
    }
}

// ============ P2/P3: flash PV over stored scores (trans=0: co_D, trans=1: co_S) ====
__global__ __launch_bounds__(512, 2)
void coattn_pv(const float* __restrict__ Sp, const float* __restrict__ Dp,
               float* __restrict__ outp,
               const unsigned short* __restrict__ Vimg,
               const unsigned short* __restrict__ scores,
               const int trans)
{
    const int s  = blockIdx.x;     // 256 = qb32 x b8
    const int b  = s & 7;
    const int qb = s >> 3;
    const int q0 = qb * QBLK;

    const float* Qg = (trans ? Sp : Dp) + (size_t)b * LSEQ * DIM;
    float* Og = outp + (size_t)(trans ? 1 : 0) * ((size_t)B_ * LSEQ * DIM) + (size_t)b * LSEQ * DIM;
    const unsigned short* vbase = Vimg + (size_t)((trans ? 1 : 0) * 8 + b) * 8 * 16 * TILE_US;
    const unsigned short* scb = scores + (size_t)b * LSEQ * LSEQ;

    __shared__ unsigned short Rr[3][16384];   // 96 KB V ring
    __shared__ unsigned short Pst[QBLK * 128];// 16 KB score/P tile, swizzled rows
    __shared__ float alf[QBLK];

    const int t    = threadIdx.x;
    const int lane = t & 63;
    const int w    = t >> 6;
    const int l31  = lane & 31;
    const int hi   = lane >> 5;
    const int ksub = w & 3;
    const int qh   = w >> 2;

    const int qrow = qh * 32 + l31;
    const int qswz = (qrow & 15);
    const int dcl  = ksub * 32 + l31;
    const int vswz = (dcl & 15) << 3;

    const int srow = t >> 3;       // softmax: row 0..63
    const int soct = t & 7;        // 8 threads per row, 16 k each

    f32x16 O[NBAND];
    #pragma unroll
    for (int i = 0; i < NBAND; ++i)
        #pragma unroll
        for (int r = 0; r < 16; ++r) O[i][r] = 0.0f;

    float m_run = -INFINITY, l_run = 0.0f;

    #define PV_MMA(BAND, SLOT)                                                    \
    do {                                                                          \
        const unsigned short* Vb = Rr[SLOT];                                      \
        __builtin_amdgcn_s_setprio(1);                                            \
        _Pragma("unroll")                                                         \
        for (int kc = 0; kc < 8; ++kc) {                                          \
            const int kk0 = kc * 16 + hi * 8;                                     \
            f16x8 vb = *(const f16x8*)&Vb[dcl * 128 + (kk0 ^ vswz)];              \
            O[BAND] = __builtin_amdgcn_mfma_f32_32x32x16_f16(pa[kc], vb, O[BAND], 0, 0, 0); \
        }                                                                         \
        __builtin_amdgcn_s_setprio(0);                                            \
    } while (0)

    #define ISSUE_V(VI, SL) issue32(vbase + (size_t)((VI) * 16 + kb) * TILE_US, Rr[SL], w, lane)

    #pragma unroll 1
    for (int kb = 0; kb < NKB; ++kb) {
        BAR();   // closes prev kb's readers of Rr[0], Rr[1], Pst

        if (!trans) {
            // DMA-gather score tile [64q][128k] into swizzled rows (pre-swizzled source)
            #pragma unroll
            for (int j = 0; j < 2; ++j) {
                const int G = (w * 2 + j) * 64 + lane;    // granule 0..1023
                const int qq = G >> 4, gg = G & 15;
                const unsigned short* src = scb + (size_t)(q0 + qq) * LSEQ + kb * 128
                                          + ((gg ^ (qq & 15)) << 3);
                gll16(src, (char*)Pst + G * 16);
            }
        }
        ISSUE_V(0, 0);
        ISSUE_V(1, 1);
        if (!trans) { VMCNT(8); }   // score tile landed (V0,V1 = 8 ops remain)
        BAR();

        if (trans) {
            // transpose-stage [64 sc][128 dr] from scores[dr][sc], pk2 along dr
            const int drp = t >> 3;            // dr-pair 0..63
            const int oct = t & 7;             // sc-oct
            const unsigned short* s0 = scb + (size_t)(kb * 128 + 2 * drp) * LSEQ + q0 + oct * 8;
            const uint4 a  = *(const uint4*)s0;
            const uint4 bb = *(const uint4*)(s0 + LSEQ);
            const unsigned short* au = (const unsigned short*)&a;
            const unsigned short* bu = (const unsigned short*)&bb;
            #pragma unroll
            for (int i = 0; i < 8; ++i) {
                const int sc = oct * 8 + i;
                const unsigned v = (unsigned)au[i] | ((unsigned)bu[i] << 16);
                *(unsigned*)((char*)Pst + sc * 256 + ((((drp >> 2) ^ (sc & 15)) << 4) + (drp & 3) * 4)) = v;
            }
            LGKM0(); BAR();
        }

        // ---- row softmax on Pst (8 threads/row, in-wave shfl reduce) ----
        {
            const int g0 = soct * 2;
            char* a0 = (char*)Pst + srow * 256 + (((g0    ) ^ (srow & 15)) << 4);
            char* a1 = (char*)Pst + srow * 256 + (((g0 + 1) ^ (srow & 15)) << 4);
            f16x8 v0 = *(const f16x8*)a0;
            f16x8 v1 = *(const f16x8*)a1;
            float sv[16];
            #pragma unroll
            for (int i = 0; i < 8; ++i) { sv[i] = (float)v0[i]; sv[8 + i] = (float)v1[i]; }
            float rm = sv[0];
            #pragma unroll
            for (int i = 1; i < 16; ++i) rm = fmaxf(rm, sv[i]);
            rm = fmaxf(rm, __shfl_xor(rm, 1));
            rm = fmaxf(rm, __shfl_xor(rm, 2));
            rm = fmaxf(rm, __shfl_xor(rm, 4));
            const float mn = fmaxf(m_run, rm);
            const float al = __expf(m_run - mn);
            float ps = 0.0f;
            #pragma unroll
            for (int i = 0; i < 16; ++i) { sv[i] = __expf(sv[i] - mn); ps += sv[i]; }
            ps += __shfl_xor(ps, 1);
            ps += __shfl_xor(ps, 2);
            ps += __shfl_xor(ps, 4);
            l_run = l_run * al + ps;
            m_run = mn;
            uint4 o0, o1;
            o0.x = pk2(sv[0], sv[1]);  o0.y = pk2(sv[2], sv[3]);
            o0.z = pk2(sv[4], sv[5]);  o0.w = pk2(sv[6], sv[7]);
            o1.x = pk2(sv[8], sv[9]);  o1.y = pk2(sv[10], sv[11]);
            o1.z = pk2(sv[12], sv[13]); o1.w = pk2(sv[14], sv[15]);
            *(uint4*)a0 = o0;
            *(uint4*)a1 = o1;
            if (soct == 0) alf[srow] = al;
        }
        LGKM0(); VMCNT(4); BAR();    // P published; own V0 drained -> published

        // pa + O rescale
        f16x8 pa[8];
        #pragma unroll
        for (int kc = 0; kc < 8; ++kc)
            pa[kc] = *(const f16x8*)((char*)Pst + qrow * 256 + (((2 * kc + hi) ^ qswz) << 4));
        {
            float alr[16];
            #pragma unroll
            for (int r = 0; r < 16; ++r)
                alr[r] = alf[qh * 32 + (r & 3) + 8 * (r >> 2) + 4 * hi];
            #pragma unroll
            for (int i = 0; i < NBAND; ++i)
                #pragma unroll
                for (int r = 0; r < 16; ++r) O[i][r] *= alr[r];
        }

        // ---- PV bands 0..7: issue; drain next; MMA current; publish ----
        ISSUE_V(2, 2); VMCNT(4); PV_MMA(0, 0); BAR();
        ISSUE_V(3, 0); VMCNT(4); PV_MMA(1, 1); BAR();
        ISSUE_V(4, 1); VMCNT(4); PV_MMA(2, 2); BAR();
        ISSUE_V(5, 2); VMCNT(4); PV_MMA(3, 0); BAR();
        ISSUE_V(6, 0); VMCNT(4); PV_MMA(4, 1); BAR();
        ISSUE_V(7, 1); VMCNT(4); PV_MMA(5, 2); BAR();
        VMCNT(0);      PV_MMA(6, 0); BAR();
        PV_MMA(7, 1);
    }

    // ---- epilogue: out = residual(Q) + O / l ----
    __syncthreads();
    if (soct == 0) alf[srow] = 1.0f / l_run;
    __syncthreads();
    #pragma unroll
    for (int r = 0; r < 16; ++r) {
        const int qr = qh * 32 + (r & 3) + 8 * (r >> 2) + 4 * hi;
        const float il = alf[qr];
        const size_t rowoff = (size_t)(q0 + qr) * DIM;
        #pragma unroll
        for (int band = 0; band < NBAND; ++band) {
            const int dcol = band * 128 + ksub * 32 + l31;
            Og[rowoff + dcol] = Qg[rowoff + dcol] + O[band][r] * il;
        }
    }
    #undef PV_MMA
    #undef ISSUE_V
    #undef QK_MMA
}

// ============ R10 main (verbatim) — used when 128MB <= ws < 192MB ============
__global__ __launch_bounds__(512, 2)
void coattn_main(const float* __restrict__ Sp, const float* __restrict__ Dp,
                 float* __restrict__ outp,
                 const unsigned short* __restrict__ Kimg,
                 const unsigned short* __restrict__ Vimg)
{
    const int s   = blockIdx.x;
    const int g   = (s & 7) | ((s >> 8) << 3);
    const int qb  = (s >> 3) & 31;
    const int dir = g >> 3;
    const int b   = g & 7;
    const int mat_k = dir;
    const int mat_q = 1 - dir;

    const float* Qg = (dir ? Sp : Dp) + (size_t)b * LSEQ * DIM;
    float* Og = outp + (size_t)dir * ((size_t)B_ * LSEQ * DIM) + (size_t)b * LSEQ * DIM;
    const int q0 = qb * QBLK;

    const unsigned short* kbase = Kimg + (size_t)(mat_k * 8 + b) * 16 * 8 * TILE_US;
    const unsigned short* qbase = Kimg + (size_t)(mat_q * 8 + b) * 16 * 8 * TILE_US
                                + (size_t)(qb >> 1) * 8 * TILE_US + (size_t)(qb & 1) * 8192;
    const unsigned short* vbase = Vimg + (size_t)(mat_k * 8 + b) * 8 * 16 * TILE_US;

    __shared__ unsigned short Rr[3][16384];
    __shared__ unsigned short QR_[3][8192];
    __shared__ float redmax[2][4][32];
    __shared__ float redsum[2][4][32];
    __shared__ float alf[QBLK];

    const int t    = threadIdx.x;
    const int lane = t & 63;
    const int w    = t >> 6;
    const int l31  = lane & 31;
    const int hi   = lane >> 5;
    const int ksub = w & 3;
    const int qh   = w >> 2;

    const int krow = ksub * 32 + l31;
    const int qrow = qh * 32 + l31;
    const int kswz = (krow & 15) << 3;
    const int qswz = (qrow & 15) << 3;
    const int dcl  = ksub * 32 + l31;
    const int vswz = (dcl & 15) << 3;

    unsigned short* Plds = QR_[0];

    f32x16 O[NBAND];
    #pragma unroll
    for (int i = 0; i < NBAND; ++i)
        #pragma unroll
        for (int r = 0; r < 16; ++r) O[i][r] = 0.0f;

    float m_run = -INFINITY, l_run = 0.0f;

    #define QK_MMA(SLOT)                                                          \
    do {                                                                          \
        const unsigned short* Kb = Rr[SLOT];                                      \
        const unsigned short* Qb = QR_[SLOT];                                     \
        __builtin_amdgcn_s_setprio(1);                                            \
        _Pragma("unroll")                                                         \
        for (int kc = 0; kc < 8; ++kc) {                                          \
            const int d0 = kc * 16 + hi * 8;                                      \
            f16x8 a  = *(const f16x8*)&Kb[krow * 128 + (d0 ^ kswz)];              \
            f16x8 bq = *(const f16x8*)&Qb[qrow * 128 + (d0 ^ qswz)];              \
            C = __builtin_amdgcn_mfma_f32_32x32x16_f16(a, bq, C, 0, 0, 0);        \
        }                                                                         \
        __builtin_amdgcn_s_setprio(0);                                            \
    } while (0)

    #define PV_MMA(BAND, SLOT)                                                    \
    do {                                                                          \
        const unsigned short* Vb = Rr[SLOT];                                      \
        __builtin_amdgcn_s_setprio(1);                                            \
        _Pragma("unroll")                                                         \
        for (int kc = 0; kc < 8; ++kc) {                                          \
            const int kk0 = kc * 16 + hi * 8;                                     \
            f16x8 vb = *(const f16x8*)&Vb[dcl * 128 + (kk0 ^ vswz)];              \
            O[BAND] = __builtin_amdgcn_mfma_f32_32x32x16_f16(pa[kc], vb, O[BAND], 0, 0, 0); \
        }                                                                         \
        __builtin_amdgcn_s_setprio(0);                                            \
    } while (0)

    #pragma unroll 1
    for (int kb = 0; kb < NKB; ++kb) {
        const unsigned short* kt = kbase + (size_t)kb * 8 * TILE_US;

        f32x16 C;
        #pragma unroll
        for (int r = 0; r < 16; ++r) C[r] = 0.0f;

        BAR();
        issue32(kt + 0 * TILE_US, Rr[0], w, lane);
        issue16(qbase + 0 * TILE_US, QR_[0], w, lane);
        issue32(kt + 1 * TILE_US, Rr[1], w, lane);
        issue16(qbase + 1 * TILE_US, QR_[1], w, lane);
        VMCNT(6);
        BAR();

        issue32(kt + 2 * TILE_US, Rr[2], w, lane);
        issue16(qbase + 2 * TILE_US, QR_[2], w, lane);
        VMCNT(6);
        QK_MMA(0);

        BAR();
        issue32(kt + 3 * TILE_US, Rr[0], w, lane);
        issue16(qbase + 3 * TILE_US, QR_[0], w, lane);
        VMCNT(6);
        QK_MMA(1);

        BAR();
        issue32(kt + 4 * TILE_US, Rr[1], w, lane);
        issue16(qbase + 4 * TILE_US, QR_[1], w, lane);
        VMCNT(6);
        QK_MMA(2);

        BAR();
        issue32(kt + 5 * TILE_US, Rr[2], w, lane);
        issue16(qbase + 5 * TILE_US, QR_[2], w, lane);
        VMCNT(6);
        QK_MMA(0);

        BAR();
        issue32(kt + 6 * TILE_US, Rr[0], w, lane);
        issue16(qbase + 6 * TILE_US, QR_[0], w, lane);
        VMCNT(6);
        QK_MMA(1);

        BAR();
        issue32(kt + 7 * TILE_US, Rr[1], w, lane);
        issue16(qbase + 7 * TILE_US, QR_[1], w, lane);
        VMCNT(6);
        QK_MMA(2);

        BAR();
        issue32(vbase + (size_t)(0 * 16 + kb) * TILE_US, Rr[2], w, lane);
        VMCNT(4);
        QK_MMA(0);

        BAR();
        issue32(vbase + (size_t)(1 * 16 + kb) * TILE_US, Rr[0], w, lane);
        VMCNT(4);
        QK_MMA(1);

        float rm = -INFINITY;
        #pragma unroll
        for (int r = 0; r < 16; ++r) rm = fmaxf(rm, C[r]);
        rm = fmaxf(rm, __shfl_xor(rm, 32));
        if (lane < 32) redmax[qh][ksub][l31] = rm;
        __syncthreads();

        const float bm = fmaxf(fmaxf(redmax[qh][0][l31], redmax[qh][1][l31]),
                               fmaxf(redmax[qh][2][l31], redmax[qh][3][l31]));
        const float mn = fmaxf(m_run, bm);
        const float al = __expf(m_run - mn);
        float p[16];
        float ps = 0.0f;
        #pragma unroll
        for (int r = 0; r < 16; ++r) { p[r] = __expf(C[r] - mn); ps += p[r]; }
        ps += __shfl_xor(ps, 32);
        if (lane < 32) {
            redsum[qh][ksub][l31] = ps;
            if (ksub == 0) alf[qh * 32 + l31] = al;
        }
        {
            #pragma unroll
            for (int rp = 0; rp < 8; ++rp) {
                const int r  = rp * 2;
                const int kk = ksub * 32 + (r & 3) + 8 * (r >> 2) + 4 * hi;
                *(unsigned*)&Plds[qrow * KBLK + (kk ^ qswz)] = pk2(p[r], p[r + 1]);
            }
        }
        __syncthreads();

        const float bs = redsum[qh][0][l31] + redsum[qh][1][l31] +
                         redsum[qh][2][l31] + redsum[qh][3][l31];
        l_run = l_run * al + bs;
        m_run = mn;

        float alr[16];
        #pragma unroll
        for (int r = 0; r < 16; ++r)
            alr[r] = alf[qh * 32 + (r & 3) + 8 * (r >> 2) + 4 * hi];
        #pragma unroll
        for (int i = 0; i < NBAND; ++i)
            #pragma unroll
            for (int r = 0; r < 16; ++r) O[i][r] *= alr[r];

        f16x8 pa[8];
        #pragma unroll
        for (int kc = 0; kc < 8; ++kc) {
            const int kk0 = kc * 16 + hi * 8;
            pa[kc] = *(const f16x8*)&Plds[qrow * KBLK + (kk0 ^ qswz)];
        }

        issue32(vbase + (size_t)(2 * 16 + kb) * TILE_US, Rr[1], w, lane);
        VMCNT(4);
        PV_MMA(0, 2);

        BAR();
        issue32(vbase + (size_t)(3 * 16 + kb) * TILE_US, Rr[2], w, lane);
        VMCNT(4);
        PV_MMA(1, 0);

        BAR();
        issue32(vbase + (size_t)(4 * 16 + kb) * TILE_US, Rr[0], w, lane);
        VMCNT(4);
        PV_MMA(2, 1);

        BAR();
        issue32(vbase + (size_t)(5 * 16 + kb) * TILE_US, Rr[1], w, lane);
        VMCNT(4);
        PV_MMA(3, 2);

        BAR();
        issue32(vbase + (size_t)(6 * 16 + kb) * TILE_US, Rr[2], w, lane);
        VMCNT(4);
        PV_MMA(4, 0);

        BAR();
        issue32(vbase + (size_t)(7 * 16 + kb) * TILE_US, Rr[0], w, lane);
        VMCNT(4);
        PV_MMA(5, 1);

        BAR();
        PV_MMA(6, 2);

        BAR();
        VMCNT(0);
        PV_MMA(7, 0);
    }

    __syncthreads();
    if (lane < 32 && ksub == 0) alf[qh * 32 + l31] = 1.0f / l_run;
    __syncthreads();
    #pragma unroll
    for (int r = 0; r < 16; ++r) {
        const int qr = qh * 32 + (r & 3) + 8 * (r >> 2) + 4 * hi;
        const float il = alf[qr];
        const size_t rowoff = (size_t)(q0 + qr) * DIM;
        #pragma unroll
        for (int band = 0; band < NBAND; ++band) {
            const int dcol = band * 128 + ksub * 32 + l31;
            Og[rowoff + dcol] = Qg[rowoff + dcol] + O[band][r] * il;
        }
    }
    #undef QK_MMA
    #undef PV_MMA
}

// ============ fallback (round-2 kernel, verbatim — used if ws too small) ============
#define NDC   8

__global__ __launch_bounds__(512, 2)
void coattn_fb(const float* __restrict__ Sp, const float* __restrict__ Dp,
               float* __restrict__ outp)
{
    const int s   = blockIdx.x;
    const int g   = (s & 7) | ((s >> 8) << 3);
    const int qb  = (s >> 3) & 31;
    const int dir = g >> 3;
    const int b   = g & 7;

    const float* Qg = (dir ? Sp : Dp) + (size_t)b * LSEQ * DIM;
    const float* Kg = (dir ? Dp : Sp) + (size_t)b * LSEQ * DIM;
    float* Og = outp + (size_t)dir * ((size_t)B_ * LSEQ * DIM) + (size_t)b * LSEQ * DIM;
    const int q0 = qb * QBLK;

    __shared__ unsigned short Klds[KBLK * 128];
    __shared__ unsigned short Qlds[QBLK * 128];
    __shared__ unsigned short Plds[QBLK * KBLK];
    __shared__ unsigned short Vlds[128 * KBLK];
    __shared__ float redmax[2][4][32];
    __shared__ float redsum[2][4][32];
    __shared__ float alf[QBLK];

    const int t    = threadIdx.x;
    const int lane = t & 63;
    const int w    = t >> 6;
    const int l31  = lane & 31;
    const int hi   = lane >> 5;
    const int ksub = w & 3;
    const int qh   = w >> 2;

    f32x16 O[NBAND];
    #pragma unroll
    for (int i = 0; i < NBAND; ++i)
        #pragma unroll
        for (int r = 0; r < 16; ++r) O[i][r] = 0.0f;

    float m_run = -INFINITY, l_run = 0.0f;

    const int srow = t >> 4;
    const int fcol = (t & 15) << 2;
    const int vmm  = t & 31;
    const int vkp0 = t >> 5;

    const int krow = ksub * 32 + l31;
    const int qrow = qh * 32 + l31;

    for (int kb = 0; kb < NKB; ++kb) {
        const int k0g = kb * KBLK;
        f32x16 C;
        #pragma unroll
        for (int r = 0; r < 16; ++r) C[r] = 0.0f;

        float4 kreg[8], qreg[4];
        #pragma unroll
        for (int pass = 0; pass < 4; ++pass)
            #pragma unroll
            for (int h = 0; h < 2; ++h)
                kreg[pass * 2 + h] = *(const float4*)(Kg + (size_t)(k0g + pass * 32 + srow) * DIM + fcol + h * 64);
        #pragma unroll
        for (int pass = 0; pass < 2; ++pass)
            #pragma unroll
            for (int h = 0; h < 2; ++h)
                qreg[pass * 2 + h] = *(const float4*)(Qg + (size_t)(q0 + pass * 32 + srow) * DIM + fcol + h * 64);

        #pragma unroll 1
        for (int dc = 0; dc < NDC; ++dc) {
            __syncthreads();
            #pragma unroll
            for (int pass = 0; pass < 4; ++pass)
                #pragma unroll
                for (int h = 0; h < 2; ++h) {
                    const int row = pass * 32 + srow;
                    const int d   = fcol + h * 64;
                    const float4 v = kreg[pass * 2 + h];
                    *(uint2*)&Klds[row * 128 + (d ^ ((row & 7) << 3))] =
                        make_uint2(pk2(v.x, v.y), pk2(v.z, v.w));
                }
            #pragma unroll
            for (int pass = 0; pass < 2; ++pass)
                #pragma unroll
                for (int h = 0; h < 2; ++h) {
                    const int row = pass * 32 + srow;
                    const int d   = fcol + h * 64;
                    const float4 v = qreg[pass * 2 + h];
                    *(uint2*)&Qlds[row * 128 + (d ^ ((row & 7) << 3))] =
                        make_uint2(pk2(v.x, v.y), pk2(v.z, v.w));
                }
            __syncthreads();
            if (dc + 1 < NDC) {
                const int dbase = (dc + 1) * 128;
                #pragma unroll
                for (int pass = 0; pass < 4; ++pass)
                    #pragma unroll
                    for (int h = 0; h < 2; ++h)
                        kreg[pass * 2 + h] = *(const float4*)(Kg + (size_t)(k0g + pass * 32 + srow) * DIM + dbase + fcol + h * 64);
                #pragma unroll
                for (int pass = 0; pass < 2; ++pass)
                    #pragma unroll
                    for (int h = 0; h < 2; ++h)
                        qreg[pass * 2 + h] = *(const float4*)(Qg + (size_t)(q0 + pass * 32 + srow) * DIM + dbase + fcol + h * 64);
            }
            #pragma unroll
            for (int kc = 0; kc < 8; ++kc) {
                const int d0 = kc * 16 + hi * 8;
                f16x8 a  = *(const f16x8*)&Klds[krow * 128 + (d0 ^ ((krow & 7) << 3))];
                f16x8 bq = *(const f16x8*)&Qlds[qrow * 128 + (d0 ^ ((qrow & 7) << 3))];
                C = __builtin_amdgcn_mfma_f32_32x32x16_f16(a, bq, C, 0, 0, 0);
            }
        }

        float rm = -INFINITY;
        #pragma unroll
        for (int r = 0; r < 16; ++r) rm = fmaxf(rm, C[r]);
        rm = fmaxf(rm, __shfl_xor(rm, 32));
        if (lane < 32) redmax[qh][ksub][l31] = rm;
        __syncthreads();

        const float bm = fmaxf(fmaxf(redmax[qh][0][l31], redmax[qh][1][l31]),
                               fmaxf(redmax[qh][2][l31], redmax[qh][3][l31]));
        const float mn = fmaxf(m_run, bm);
        const float al = __expf(m_run - mn);
        float p[16];
        float ps = 0.0f;
        #pragma unroll
        for (int r = 0; r < 16; ++r) { p[r] = __expf(C[r] - mn); ps += p[r]; }
        ps += __shfl_xor(ps, 32);
        if (lane < 32) {
            redsum[qh][ksub][l31] = ps;
            if (ksub == 0) alf[qh * 32 + l31] = al;
        }
        {
            #pragma unroll
            for (int rp = 0; rp < 8; ++rp) {
                const int r  = rp * 2;
                const int kk = ksub * 32 + (r & 3) + 8 * (r >> 2) + 4 * hi;
                *(unsigned*)&Plds[qrow * KBLK + (kk ^ ((qrow & 7) << 3))] = pk2(p[r], p[r + 1]);
            }
        }
        __syncthreads();

        const float bs = redsum[qh][0][l31] + redsum[qh][1][l31] +
                         redsum[qh][2][l31] + redsum[qh][3][l31];
        l_run = l_run * al + bs;
        m_run = mn;

        float alr[16];
        #pragma unroll
        for (int r = 0; r < 16; ++r)
            alr[r] = alf[qh * 32 + (r & 3) + 8 * (r >> 2) + 4 * hi];
        #pragma unroll
        for (int i = 0; i < NBAND; ++i)
            #pragma unroll
            for (int r = 0; r < 16; ++r) O[i][r] *= alr[r];

        f16x8 pa[8];
        #pragma unroll
        for (int kc = 0; kc < 8; ++kc) {
            const int kk0 = kc * 16 + hi * 8;
            pa[kc] = *(const f16x8*)&Plds[qrow * KBLK + (kk0 ^ ((qrow & 7) << 3))];
        }

        float4 v0s[4], v1s[4];
        #pragma unroll
        for (int pass = 0; pass < 4; ++pass) {
            const int kp = pass * 16 + vkp0;
            v0s[pass] = *(const float4*)(Kg + (size_t)(k0g + 2 * kp) * DIM + vmm * 4);
            v1s[pass] = *(const float4*)(Kg + (size_t)(k0g + 2 * kp + 1) * DIM + vmm * 4);
        }

        #pragma unroll
        for (int band = 0; band < NBAND; ++band) {
            __syncthreads();
            #pragma unroll
            for (int pass = 0; pass < 4; ++pass) {
                const int kp = pass * 16 + vkp0;
                const float* a0 = (const float*)&v0s[pass];
                const float* a1 = (const float*)&v1s[pass];
                #pragma unroll
                for (int j = 0; j < 4; ++j) {
                    const int dclw = vmm * 4 + j;
                    *(unsigned*)&Vlds[dclw * KBLK + ((2 * kp) ^ ((dclw & 7) << 3))] = pk2(a0[j], a1[j]);
                }
            }
            __syncthreads();
            if (band + 1 < NBAND) {
                const int cb = (band + 1) * 128;
                #pragma unroll
                for (int pass = 0; pass < 4; ++pass) {
                    const int kp = pass * 16 + vkp0;
                    v0s[pass] = *(const float4*)(Kg + (size_t)(k0g + 2 * kp) * DIM + cb + vmm * 4);
                    v1s[pass] = *(const float4*)(Kg + (size_t)(k0g + 2 * kp + 1) * DIM + cb + vmm * 4);
                }
            }
            const int dclr = ksub * 32 + l31;
            const int sw  = (dclr & 7) << 3;
            #pragma unroll
            for (int kc = 0; kc < 8; ++kc) {
                const int kk0 = kc * 16 + hi * 8;
                f16x8 vb = *(const f16x8*)&Vlds[dclr * KBLK + (kk0 ^ sw)];
                O[band] = __builtin_amdgcn_mfma_f32_32x32x16_f16(pa[kc], vb, O[band], 0, 0, 0);
            }
        }
    }

    if (lane < 32 && ksub == 0) alf[qh * 32 + l31] = 1.0f / l_run;
    __syncthreads();
    #pragma unroll
    for (int r = 0; r < 16; ++r) {
        const int qr = qh * 32 + (r & 3) + 8 * (r >> 2) + 4 * hi;
        const float il = alf[qr];
        const size_t rowoff = (size_t)(q0 + qr) * DIM;
        #pragma unroll
        for (int band = 0; band < NBAND; ++band) {
            const int dcol = band * 128 + ksub * 32 + l31;
            Og[rowoff + dcol] = Qg[rowoff + dcol] + O[band][r] * il;
        }
    }
}

extern "C" void kernel_launch(void* const* d_in, const int* in_sizes, int n_in,
                              void* d_out, int out_size, void* d_ws, size_t ws_size,
                              hipStream_t stream) {
    const float* S = (const float*)d_in[0];
    const float* D = (const float*)d_in[1];
    float* out = (float*)d_out;
    if (ws_size >= WS_NEW) {
        unsigned short* Kimg   = (unsigned short*)d_ws;
        unsigned short* Vimg   = Kimg + KIMG_US;
        unsigned short* scores = Vimg + KIMG_US;
        prepass<<<dim3(2048, 1, 1), dim3(256, 1, 1), 0, stream>>>(S, D, Kimg, Vimg);
        coattn_qk<<<dim3(256, 1, 1), dim3(512, 1, 1), 0, stream>>>(Kimg, scores);
        coattn_pv<<<dim3(256, 1, 1), dim3(512, 1, 1), 0, stream>>>(S, D, out, Vimg, scores, 0);
        coattn_pv<<<dim3(256, 1, 1), dim3(512, 1, 1), 0, stream>>>(S, D, out, Vimg, scores, 1);
    } else if (ws_size >= WS_NEED) {
        unsigned short* Kimg = (unsigned short*)d_ws;
        unsigned short* Vimg = Kimg + KIMG_US;
        prepass<<<dim3(2048, 1, 1), dim3(256, 1, 1), 0, stream>>>(S, D, Kimg, Vimg);
        coattn_main<<<dim3(512, 1, 1), dim3(512, 1, 1), 0, stream>>>(S, D, out, Kimg, Vimg);
    } else {
        coattn_fb<<<dim3(512, 1, 1), dim3(512, 1, 1), 0, stream>>>(S, D, out);
    }
}